// Round 1
// baseline (73.099 us; speedup 1.0000x reference)
//
#include <hip/hip_runtime.h>
#include <stdint.h>

// MajFC: out[b,c] = 2.25 * sum_g clip(sum_{k<3} sign(x[b,3g+k])*sign(w[c,3g+k]), -1, 1)
// Sign-only bitplanes (absmax 0.0 verified previous session): t = px ^ pw,
// clip(group) = 1 - 2*maj(t0,t1,t2), out = 2.25*(1024 - 2*popc_total) = 2304 - 4.5*popc.
//
// Permutation trick (unchanged): element e = 768q + 12l + 3j + k -> plane [q][3j+k]
// bit l, applied identically to x and w, leaves the popc-sum invariant.
//
// R9 structural change vs R8: w never crosses the dispatch boundary.
//   1) pack_x: x only (3.1 MB read, 256 blocks). The serialized prologue shrinks
//      ~5x (was 15.7 MB: all of w+x had to land in ws before any compute).
//   2) fused_maj: 512 blocks; block = c-pair x all 256 b. Reads its 2 raw w rows
//      exactly once (w read once chip-wide, overlapped with compute across blocks),
//      ballots into 768 B LDS, then per-thread (= b-row) coalesced xpk loads from
//      L2 + LDS-broadcast w planes. wpk round-trip (384 KB write + 50 MB L2
//      re-read) eliminated.
// Two dispatches kept: cross-block release/acquire fences measured ~60us (R3/R5).

#define C_IN  3072
#define C_OUT 1024

// ws layout: xpk [b][q][12] uint64 -> 98304 B (96 B contiguous per (b,q), 16B-aligned)

__global__ __launch_bounds__(256) void pack_x(const float* __restrict__ x,
                                              uint64_t* __restrict__ xpk) {
    int j    = blockIdx.x * 4 + (threadIdx.x >> 6);   // chunk-job 0..1023 = b*4+q
    int lane = threadIdx.x & 63;
    int b = j >> 2, q = j & 3;
    const float4* s4 = (const float4*)(x + (size_t)b * C_IN + q * 768 + 12 * lane);
    float4 f0 = s4[0], f1 = s4[1], f2 = s4[2];
    float v[12] = {f0.x, f0.y, f0.z, f0.w,
                   f1.x, f1.y, f1.z, f1.w,
                   f2.x, f2.y, f2.z, f2.w};
    uint64_t pl[12];
#pragma unroll
    for (int m = 0; m < 12; ++m)
        pl[m] = __ballot(v[m] > 0.0f);
    if (lane == 0) {
        uint64_t* dst = xpk + ((size_t)b * 4 + q) * 12;
#pragma unroll
        for (int m = 0; m < 12; ++m)
            dst[m] = pl[m];   // ballots wave-uniform; 96 B contiguous
    }
}

// ---- fused w-pack + majority: block = (c0, c0+1) x all 256 b ----------------
__global__ __launch_bounds__(256) void fused_maj(const float* __restrict__ w,
                                                 const uint64_t* __restrict__ xpk,
                                                 float* __restrict__ out) {
    __shared__ uint64_t wpl[8][12];    // [c_local*4 + q][m], 768 B
    const int tid  = threadIdx.x;
    const int lane = tid & 63;
    const int wv   = tid >> 6;         // wave 0..3
    const int c0   = blockIdx.x * 2;   // 512 blocks -> c-pairs 0..1022

    // phase A: pack 2 w rows (8 chunks; wave wv does q=wv for both c rows)
    for (int h = wv; h < 8; h += 4) {
        int cl = h >> 2, q = h & 3;
        const float4* s4 = (const float4*)(w + (size_t)(c0 + cl) * C_IN + q * 768 + 12 * lane);
        float4 f0 = s4[0], f1 = s4[1], f2 = s4[2];
        float v[12] = {f0.x, f0.y, f0.z, f0.w,
                       f1.x, f1.y, f1.z, f1.w,
                       f2.x, f2.y, f2.z, f2.w};
        uint64_t pl[12];
#pragma unroll
        for (int m = 0; m < 12; ++m)
            pl[m] = __ballot(v[m] > 0.0f);
        if (lane == 0) {
#pragma unroll
            for (int m = 0; m < 12; ++m)
                wpl[h][m] = pl[m];
        }
    }
    __syncthreads();

    // phase B: thread = one b-row, two c outputs; x per-lane from L2, w via LDS broadcast
    const int b = tid;
    int acc0 = 0, acc1 = 0;
#pragma unroll
    for (int q = 0; q < 4; ++q) {
        const uint64_t* xb = xpk + ((size_t)b * 4 + q) * 12;   // 96 B contiguous/lane
        uint64_t X[12];
#pragma unroll
        for (int m = 0; m < 12; ++m) X[m] = xb[m];
#pragma unroll
        for (int j = 0; j < 4; ++j) {
            uint64_t t0 = X[3 * j + 0] ^ wpl[q][3 * j + 0];
            uint64_t t1 = X[3 * j + 1] ^ wpl[q][3 * j + 1];
            uint64_t t2 = X[3 * j + 2] ^ wpl[q][3 * j + 2];
            acc0 += __popcll((t0 & t1) | (t2 & (t0 | t1)));
            uint64_t u0 = X[3 * j + 0] ^ wpl[4 + q][3 * j + 0];
            uint64_t u1 = X[3 * j + 1] ^ wpl[4 + q][3 * j + 1];
            uint64_t u2 = X[3 * j + 2] ^ wpl[4 + q][3 * j + 2];
            acc1 += __popcll((u0 & u1) | (u2 & (u0 | u1)));
        }
    }
    float2 r;
    r.x = 2304.0f - 4.5f * (float)acc0;
    r.y = 2304.0f - 4.5f * (float)acc1;
    *(float2*)(out + (size_t)b * C_OUT + c0) = r;   // c0 even -> 8B aligned
}

extern "C" void kernel_launch(void* const* d_in, const int* in_sizes, int n_in,
                              void* d_out, int out_size, void* d_ws, size_t ws_size,
                              hipStream_t stream) {
    const float* x = (const float*)d_in[0];   // [256, 3072] f32
    const float* w = (const float*)d_in[1];   // [1024, 3072] f32
    float* out = (float*)d_out;               // [256, 1024] f32

    uint64_t* xpk = (uint64_t*)d_ws;          // 98304 B

    pack_x<<<256, 256, 0, stream>>>(x, xpk);
    fused_maj<<<512, 256, 0, stream>>>(w, xpk, out);
}